// Round 6
// baseline (772.647 us; speedup 1.0000x reference)
//
#include <hip/hip_runtime.h>

#define N_NODES 100000
#define N_EDGES 1600000
#define N_GRAPHS 2048
#define HID 64
#define IN_F 14
#define N_CLS 2
#define EPS 1e-5f

typedef _Float16 half_t;
typedef _Float16 half8 __attribute__((ext_vector_type(8)));
typedef float f32x4 __attribute__((ext_vector_type(4)));

#define GSTRIDE ((size_t)N_NODES * 16)   // halves per feature-group plane

// ---------------- CSR build: one packed atomic per edge ----------------
// packed[c]: high 32 = fixed-point (w * 65536) sum, low 32 = count.
// atomicAdd's returned low half = this edge's rank within bin c.
__global__ __launch_bounds__(256) void hist_rank_kernel(const int* __restrict__ col,
                                                        const float* __restrict__ w,
                                                        unsigned long long* __restrict__ packed,
                                                        int* __restrict__ rank, int E) {
    int stride = gridDim.x * blockDim.x;
    for (int e = blockIdx.x * blockDim.x + threadIdx.x; e < E; e += stride) {
        int c = col[e];
        unsigned int fx = __float2uint_rn(w[e] * 65536.0f);
        unsigned long long old =
            atomicAdd(&packed[c], ((unsigned long long)fx << 32) | 1ull);
        rank[e] = (int)(old & 0xffffffffull);
    }
}

// dinv[n] = rsqrt(1 + wsum[n])
__global__ __launch_bounds__(256) void dinv_from_packed(const unsigned long long* __restrict__ packed,
                                                        float* __restrict__ dinv, int n) {
    int i = blockIdx.x * blockDim.x + threadIdx.x;
    if (i < n) {
        float wsum = (float)(packed[i] >> 32) * (1.0f / 65536.0f);
        dinv[i] = rsqrtf(1.0f + wsum);
    }
}

// ---- exclusive scan of counts (1024 bins per block, 4 per thread) ----

__global__ __launch_bounds__(256) void blocksum1024_kernel(const unsigned long long* __restrict__ packed,
                                                           int* __restrict__ bsum, int n) {
    __shared__ int ls[256];
    int base = blockIdx.x * 1024 + threadIdx.x * 4;
    int s = 0;
#pragma unroll
    for (int k = 0; k < 4; k++) {
        int i = base + k;
        if (i < n) s += (int)(packed[i] & 0xffffffffull);
    }
    ls[threadIdx.x] = s;
    __syncthreads();
    for (int off = 128; off > 0; off >>= 1) {
        if (threadIdx.x < off) ls[threadIdx.x] += ls[threadIdx.x + off];
        __syncthreads();
    }
    if (threadIdx.x == 0) bsum[blockIdx.x] = ls[0];
}

__global__ __launch_bounds__(512) void topscan_kernel(int* __restrict__ bsum, int nb) {
    __shared__ int ls[512];
    int t = threadIdx.x;
    int v = (t < nb) ? bsum[t] : 0;
    ls[t] = v;
    __syncthreads();
    for (int off = 1; off < 512; off <<= 1) {
        int x = ls[t];
        if (t >= off) x += ls[t - off];
        __syncthreads();
        ls[t] = x;
        __syncthreads();
    }
    if (t < nb) bsum[t] = ls[t] - v;  // exclusive
}

__global__ __launch_bounds__(256) void blockscan1024_kernel(const unsigned long long* __restrict__ packed,
                                                            const int* __restrict__ bsum,
                                                            int* __restrict__ ptr, int n, int E) {
    __shared__ int ls[256];
    int base = blockIdx.x * 1024 + threadIdx.x * 4;
    int c[4];
    int s = 0;
#pragma unroll
    for (int k = 0; k < 4; k++) {
        int i = base + k;
        c[k] = (i < n) ? (int)(packed[i] & 0xffffffffull) : 0;
        s += c[k];
    }
    ls[threadIdx.x] = s;
    __syncthreads();
    for (int off = 1; off < 256; off <<= 1) {
        int x = ls[threadIdx.x];
        if (threadIdx.x >= off) x += ls[threadIdx.x - off];
        __syncthreads();
        ls[threadIdx.x] = x;
        __syncthreads();
    }
    int run = ls[threadIdx.x] - s + bsum[blockIdx.x];
#pragma unroll
    for (int k = 0; k < 4; k++) {
        int i = base + k;
        if (i < n) ptr[i] = run;
        run += c[k];
    }
    if (blockIdx.x == 0 && threadIdx.x == 0) ptr[n] = E;
}

// atomic-free permute: pos = ptr[c] + rank[e].
// Edge packed to 4 bytes: src (17 bits, [31:15]) | 15-bit float norm (fp32 bits [30:16]).
__global__ __launch_bounds__(256) void permute_kernel(const int* __restrict__ row,
                                                      const int* __restrict__ col,
                                                      const float* __restrict__ w,
                                                      const float* __restrict__ dinv,
                                                      const int* __restrict__ ptr,
                                                      const int* __restrict__ rank,
                                                      unsigned int* __restrict__ edges, int E) {
    int stride = gridDim.x * blockDim.x;
    for (int e = blockIdx.x * blockDim.x + threadIdx.x; e < E; e += stride) {
        int r = row[e], c = col[e];
        int pos = ptr[c] + rank[e];
        float nrm = dinv[r] * w[e] * dinv[c];
        unsigned int nb = __float_as_uint(nrm);
        unsigned int n15 = (nb + 0x8000u) >> 16;        // round-to-nearest, sign-free
        if (n15 > 0x7fffu) n15 = 0x7fffu;
        edges[pos] = ((unsigned int)r << 15) | n15;
    }
}

// ---------------- layer-1 GEMM (K=14, VALU), grouped store ----------------

template <int K>
__global__ __launch_bounds__(256) void gemm_kernel(const float* __restrict__ h,
                                                   const float* __restrict__ W,
                                                   half_t* __restrict__ xw, int n_nodes) {
    int f = threadIdx.x & 63;
    float wcol[K];
#pragma unroll
    for (int k = 0; k < K; k++) wcol[k] = W[k * HID + f];
    half_t* xg = xw + (size_t)(f >> 4) * GSTRIDE + (f & 15);
    int wave = (blockIdx.x * blockDim.x + threadIdx.x) >> 6;
    int nwaves = (gridDim.x * blockDim.x) >> 6;
    for (int n = wave; n < n_nodes; n += nwaves) {
        const float* hr = h + (size_t)n * K;
        float acc = 0.f;
#pragma unroll
        for (int k = 0; k < K; k++) acc += hr[k] * wcol[k];
        xg[(size_t)n * 16] = (half_t)acc;
    }
}

// ---------------- MFMA GEMM with fused BN+ReLU, grouped store ----------------
__global__ __launch_bounds__(256) void gemm_bn_mfma_kernel(const float* __restrict__ h,
                                                           const float* __restrict__ W,
                                                           const float* __restrict__ stats,
                                                           const float* __restrict__ gamma,
                                                           const float* __restrict__ beta,
                                                           half_t* __restrict__ xw, int n_nodes) {
    __shared__ float sc_s[HID], sh_s[HID];
    if (threadIdx.x < 64) {
        float mean = stats[threadIdx.x] * (1.0f / N_NODES);
        float var = stats[64 + threadIdx.x] * (1.0f / N_NODES) - mean * mean;
        float sc = gamma[threadIdx.x] * rsqrtf(var + EPS);
        sc_s[threadIdx.x] = sc;
        sh_s[threadIdx.x] = beta[threadIdx.x] - mean * sc;
    }
    __syncthreads();
    int lane = threadIdx.x & 63;
    int col16 = lane & 15;
    int quad = lane >> 4;

    float scA[2][8], shA[2][8];
#pragma unroll
    for (int kh = 0; kh < 2; kh++)
#pragma unroll
        for (int j = 0; j < 8; j++) {
            int k = kh * 32 + quad * 8 + j;
            scA[kh][j] = sc_s[k];
            shA[kh][j] = sh_s[k];
        }

    half8 bfrag[4][2];
#pragma unroll
    for (int t = 0; t < 4; t++)
#pragma unroll
        for (int kh = 0; kh < 2; kh++)
#pragma unroll
            for (int j = 0; j < 8; j++) {
                int k = kh * 32 + quad * 8 + j;
                bfrag[t][kh][j] = (half_t)W[k * HID + t * 16 + col16];
            }

    int wave = (blockIdx.x * blockDim.x + threadIdx.x) >> 6;
    int nwaves = (gridDim.x * blockDim.x) >> 6;
    int ntiles = n_nodes >> 4;
    for (int tIdx = wave; tIdx < ntiles; tIdx += nwaves) {
        int n0 = tIdx << 4;
        const float* hr = h + (size_t)(n0 + col16) * HID + quad * 8;
        half8 afrag[2];
#pragma unroll
        for (int kh = 0; kh < 2; kh++) {
            float4 p0 = *(const float4*)(hr + kh * 32);
            float4 p1 = *(const float4*)(hr + kh * 32 + 4);
            float fv[8] = {p0.x, p0.y, p0.z, p0.w, p1.x, p1.y, p1.z, p1.w};
#pragma unroll
            for (int j = 0; j < 8; j++) {
                float v = fv[j] * scA[kh][j] + shA[kh][j];
                afrag[kh][j] = (half_t)fmaxf(v, 0.f);
            }
        }
        f32x4 acc[4];
#pragma unroll
        for (int t = 0; t < 4; t++) {
            f32x4 z = {0.f, 0.f, 0.f, 0.f};
            acc[t] = __builtin_amdgcn_mfma_f32_16x16x32_f16(afrag[0], bfrag[t][0], z, 0, 0, 0);
            acc[t] = __builtin_amdgcn_mfma_f32_16x16x32_f16(afrag[1], bfrag[t][1], acc[t], 0, 0, 0);
        }
#pragma unroll
        for (int t = 0; t < 4; t++) {
            half_t* xg = xw + (size_t)t * GSTRIDE;
#pragma unroll
            for (int r = 0; r < 4; r++) {
                int rowi = n0 + quad * 4 + r;
                xg[(size_t)rowi * 16 + col16] = (half_t)acc[t][r];
            }
        }
    }
}

// ---------------- feature-grouped gather: wave per node ----------------
// Lanes = 4 edge-slots x 16 features. All 64 lanes walk the SAME node's edge
// list (wave-uniform bounds, no divergence). 64-edge window held across lanes;
// shfl-broadcast per edge; butterfly-reduce across edge-slots at node end.
__global__ __launch_bounds__(256) void gather_stats_kernel(const int* __restrict__ ptr,
                                                           const unsigned int* __restrict__ edges,
                                                           const half_t* __restrict__ xw,
                                                           const float* __restrict__ dinv,
                                                           const float* __restrict__ b,
                                                           float* __restrict__ h,
                                                           float* __restrict__ stats,
                                                           int n_nodes) {
    int g = (blockIdx.x & 7) >> 1;                           // feature group 0..3
    int grank = ((blockIdx.x >> 3) << 1) | (blockIdx.x & 1); // block rank within group
    int lane = threadIdx.x & 63;
    int lane16 = lane & 15;
    int esub = lane >> 4;                                    // edge-slot 0..3
    int waveId = grank * 4 + (threadIdx.x >> 6);
    int nwaves = gridDim.x;                                  // (gridDim/4 blocks)*4 waves

    const half_t* xg = xw + (size_t)g * GSTRIDE;
    const char* xgb = (const char*)xg + lane16 * 2;
    int f = g * 16 + lane16;
    float bf = b[f];

    float s = 0.f, s2 = 0.f;
    for (int n = waveId; n < n_nodes; n += nwaves) {
        int beg = ptr[n];
        int c = ptr[n + 1] - beg;
        float a0 = 0.f, a1 = 0.f, a2 = 0.f, a3 = 0.f;
        int j0 = 0;
        for (; j0 + 64 <= c; j0 += 64) {   // full windows: no predication
            int ev = (int)edges[beg + j0 + lane];
#pragma unroll
            for (int t = 0; t < 16; t++) {
                unsigned int u = (unsigned int)__shfl(ev, t * 4 + esub);
                float nm = __uint_as_float((u & 0x7fffu) << 16);
                float x = (float)*(const half_t*)(xgb + ((size_t)(u >> 15) << 5));
                if ((t & 3) == 0) a0 += nm * x;
                else if ((t & 3) == 1) a1 += nm * x;
                else if ((t & 3) == 2) a2 += nm * x;
                else a3 += nm * x;
            }
        }
        int m = c - j0;
        if (m > 0) {                        // tail window: predicated
            int idx = beg + j0 + lane;
            if (idx > N_EDGES - 1) idx = N_EDGES - 1;
            int ev = (int)edges[idx];
            int tMax = (m + 3) >> 2;
            for (int t = 0; t < tMax; t += 2) {
                int w0 = t * 4 + esub;
                int w1 = w0 + 4;
                unsigned int u0 = (unsigned int)__shfl(ev, w0);
                unsigned int u1 = (unsigned int)__shfl(ev, w1 & 63);
                float nm0 = (w0 < m) ? __uint_as_float((u0 & 0x7fffu) << 16) : 0.f;
                float nm1 = (t + 1 < tMax && w1 < m) ? __uint_as_float((u1 & 0x7fffu) << 16) : 0.f;
                float x0 = (float)*(const half_t*)(xgb + ((size_t)(u0 >> 15) << 5));
                float x1 = (float)*(const half_t*)(xgb + ((size_t)(u1 >> 15) << 5));
                a0 += nm0 * x0;
                a1 += nm1 * x1;
            }
        }
        float acc = (a0 + a1) + (a2 + a3);
        acc += __shfl_xor(acc, 16);
        acc += __shfl_xor(acc, 32);
        float di = dinv[n];
        float xself = (float)xg[(size_t)n * 16 + lane16];
        float v = acc + di * di * xself + bf;
        if (esub == 0) h[(size_t)n * HID + f] = v;
        s += v;          // 4x redundant across esub; scaled by 0.25 below
        s2 += v * v;
    }
    __shared__ float ls[256], ls2[256];
    ls[threadIdx.x] = s;
    ls2[threadIdx.x] = s2;
    __syncthreads();
    if (threadIdx.x < 16) {
        float a = 0.f, aa = 0.f;
#pragma unroll
        for (int k = 0; k < 16; k++) {
            a += ls[k * 16 + threadIdx.x];
            aa += ls2[k * 16 + threadIdx.x];
        }
        atomicAdd(&stats[g * 16 + threadIdx.x], a * 0.25f);
        atomicAdd(&stats[64 + g * 16 + threadIdx.x], aa * 0.25f);
    }
}

// ---------------- layer 3: BN + ReLU + write node_embs + segment-sum --------
__global__ __launch_bounds__(256) void bn_relu_seg_kernel(float* __restrict__ h,
                                                          const float* __restrict__ stats,
                                                          const float* __restrict__ gamma,
                                                          const float* __restrict__ beta,
                                                          const int* __restrict__ batch,
                                                          float* __restrict__ gemb,
                                                          int n_nodes) {
    int g = blockIdx.x * blockDim.x + threadIdx.x;
    int f = g & 63;
    int wave = g >> 6;
    int nwaves = (gridDim.x * blockDim.x) >> 6;
    int chunk = (n_nodes + nwaves - 1) / nwaves;
    int n0 = wave * chunk;
    int n1 = n0 + chunk;
    if (n1 > n_nodes) n1 = n_nodes;
    if (n0 >= n_nodes) return;
    float mean = stats[f] * (1.0f / N_NODES);
    float var = stats[64 + f] * (1.0f / N_NODES) - mean * mean;
    float sc = gamma[f] * rsqrtf(var + EPS);
    float sh = beta[f] - mean * sc;
    int curg = batch[n0];
    float racc = 0.f;
    for (int n = n0; n < n1; n++) {
        int bg = batch[n];
        if (bg != curg) {
            atomicAdd(&gemb[(size_t)curg * HID + f], racc);
            racc = 0.f;
            curg = bg;
        }
        size_t idx = (size_t)n * HID + f;
        float v = h[idx] * sc + sh;
        v = fmaxf(v, 0.f);
        h[idx] = v;
        racc += v;
    }
    atomicAdd(&gemb[(size_t)curg * HID + f], racc);
}

__global__ __launch_bounds__(256) void final_kernel(const float* __restrict__ gemb,
                                                    const float* __restrict__ fcW,
                                                    const float* __restrict__ fcb,
                                                    float* __restrict__ out) {
    int g = blockIdx.x * blockDim.x + threadIdx.x;
    if (g >= N_GRAPHS * N_CLS) return;
    int gr = g >> 1, c = g & 1;
    float acc = fcb[c];
#pragma unroll
    for (int k = 0; k < HID; k++) acc += gemb[gr * HID + k] * fcW[k * N_CLS + c];
    out[g] = acc;
}

// ---------------- launch ----------------

extern "C" void kernel_launch(void* const* d_in, const int* in_sizes, int n_in,
                              void* d_out, int out_size, void* d_ws, size_t ws_size,
                              hipStream_t stream) {
    const float* x    = (const float*)d_in[0];
    const int*   ei   = (const int*)d_in[1];
    const int*   batch= (const int*)d_in[2];
    const float* ew   = (const float*)d_in[3];
    const float* W1   = (const float*)d_in[4];
    const float* b1   = (const float*)d_in[5];
    const float* W2   = (const float*)d_in[6];
    const float* b2   = (const float*)d_in[7];
    const float* W3   = (const float*)d_in[8];
    const float* b3   = (const float*)d_in[9];
    const float* g1   = (const float*)d_in[10];
    const float* bt1  = (const float*)d_in[11];
    const float* g2   = (const float*)d_in[12];
    const float* bt2  = (const float*)d_in[13];
    const float* g3   = (const float*)d_in[14];
    const float* bt3  = (const float*)d_in[15];
    const float* fcW  = (const float*)d_in[16];
    const float* fcb  = (const float*)d_in[17];

    const int* row = ei;
    const int* col = ei + N_EDGES;

    // d_out layout: out [2048*2] | node_embs [100000*64] | graph_emb [2048*64]
    float* out_head  = (float*)d_out;
    float* node_embs = out_head + N_GRAPHS * N_CLS;
    float* gemb      = node_embs + (size_t)N_NODES * HID;

    // ws layout
    half_t* xwh  = (half_t*)d_ws;                             // 12.8 MB (4 planes)
    unsigned int* edges = (unsigned int*)(xwh + (size_t)N_NODES * HID); // 6.4 MB
    unsigned long long* packed = (unsigned long long*)(edges + N_EDGES); // 800 KB
    float* dinv  = (float*)(packed + N_NODES);                // 400 KB
    float* stats = dinv + N_NODES;                            // 512 B
    int*   ptr   = (int*)(stats + 128);                       // 400 KB (+1)
    int*   rank  = ptr + N_NODES + 1;                         // 6.4 MB
    int*   bsum  = rank + N_EDGES;                            // 512 B

    const int B   = 256;
    const int gN  = (N_NODES + B - 1) / B;
    const int NBS = (N_NODES + 1023) / 1024;  // 98 scan blocks
    const int gGS = 1024;                     // grid-stride
    const int gGA = 2048;                     // gather (mult of 8)

    // ---- CSR build: 1 packed atomic per edge, atomic-free permute ----
    hipMemsetAsync(packed, 0, N_NODES * sizeof(unsigned long long), stream);
    hist_rank_kernel<<<gGS, B, 0, stream>>>(col, ew, packed, rank, N_EDGES);
    dinv_from_packed<<<gN, B, 0, stream>>>(packed, dinv, N_NODES);
    blocksum1024_kernel<<<NBS, B, 0, stream>>>(packed, bsum, N_NODES);
    topscan_kernel<<<1, 512, 0, stream>>>(bsum, NBS);
    blockscan1024_kernel<<<NBS, B, 0, stream>>>(packed, bsum, ptr, N_NODES, N_EDGES);
    permute_kernel<<<gGS, B, 0, stream>>>(row, col, ew, dinv, ptr, rank, edges, N_EDGES);

    float* h = node_embs;  // raw (pre-BN) activation; ends as h3 output

    // ---- layer 1 ----
    gemm_kernel<IN_F><<<gGS, B, 0, stream>>>(x, W1, xwh, N_NODES);
    hipMemsetAsync(stats, 0, 128 * sizeof(float), stream);
    gather_stats_kernel<<<gGA, B, 0, stream>>>(ptr, edges, xwh, dinv, b1, h, stats, N_NODES);

    // ---- layer 2 (BN1+ReLU fused into MFMA GEMM) ----
    gemm_bn_mfma_kernel<<<gGS, B, 0, stream>>>(h, W2, stats, g1, bt1, xwh, N_NODES);
    hipMemsetAsync(stats, 0, 128 * sizeof(float), stream);
    gather_stats_kernel<<<gGA, B, 0, stream>>>(ptr, edges, xwh, dinv, b2, h, stats, N_NODES);

    // ---- layer 3 (BN2+ReLU fused into MFMA GEMM) ----
    gemm_bn_mfma_kernel<<<gGS, B, 0, stream>>>(h, W3, stats, g2, bt2, xwh, N_NODES);
    hipMemsetAsync(stats, 0, 128 * sizeof(float), stream);
    gather_stats_kernel<<<gGA, B, 0, stream>>>(ptr, edges, xwh, dinv, b3, h, stats, N_NODES);

    // ---- BN3 + ReLU + node_embs + segment-sum ----
    hipMemsetAsync(gemb, 0, (size_t)N_GRAPHS * HID * sizeof(float), stream);
    bn_relu_seg_kernel<<<gGS, B, 0, stream>>>(h, stats, g3, bt3, batch, gemb, N_NODES);

    // ---- readout ----
    final_kernel<<<(N_GRAPHS * N_CLS + B - 1) / B, B, 0, stream>>>(gemb, fcW, fcb, out_head);
}

// Round 7
// 493.924 us; speedup vs baseline: 1.5643x; 1.5643x over previous
//
#include <hip/hip_runtime.h>

#define N_NODES 100000
#define N_EDGES 1600000
#define N_GRAPHS 2048
#define HID 64
#define IN_F 14
#define N_CLS 2
#define EPS 1e-5f

typedef _Float16 half_t;
typedef _Float16 half8 __attribute__((ext_vector_type(8)));
typedef float f32x4 __attribute__((ext_vector_type(4)));

#define GSTRIDE ((size_t)N_NODES * 16)   // halves per feature-group plane

// ---------------- CSR build: one packed atomic per edge ----------------
// packed[c]: high 32 = fixed-point (w * 65536) sum, low 32 = count.
// atomicAdd's returned low half = this edge's rank within bin c.
__global__ __launch_bounds__(256) void hist_rank_kernel(const int* __restrict__ col,
                                                        const float* __restrict__ w,
                                                        unsigned long long* __restrict__ packed,
                                                        int* __restrict__ rank, int E) {
    int stride = gridDim.x * blockDim.x;
    for (int e = blockIdx.x * blockDim.x + threadIdx.x; e < E; e += stride) {
        int c = col[e];
        unsigned int fx = __float2uint_rn(w[e] * 65536.0f);
        unsigned long long old =
            atomicAdd(&packed[c], ((unsigned long long)fx << 32) | 1ull);
        rank[e] = (int)(old & 0xffffffffull);
    }
}

// dinv[n] = rsqrt(1 + wsum[n])
__global__ __launch_bounds__(256) void dinv_from_packed(const unsigned long long* __restrict__ packed,
                                                        float* __restrict__ dinv, int n) {
    int i = blockIdx.x * blockDim.x + threadIdx.x;
    if (i < n) {
        float wsum = (float)(packed[i] >> 32) * (1.0f / 65536.0f);
        dinv[i] = rsqrtf(1.0f + wsum);
    }
}

// ---- exclusive scan of counts (1024 bins per block, 4 per thread) ----

__global__ __launch_bounds__(256) void blocksum1024_kernel(const unsigned long long* __restrict__ packed,
                                                           int* __restrict__ bsum, int n) {
    __shared__ int ls[256];
    int base = blockIdx.x * 1024 + threadIdx.x * 4;
    int s = 0;
#pragma unroll
    for (int k = 0; k < 4; k++) {
        int i = base + k;
        if (i < n) s += (int)(packed[i] & 0xffffffffull);
    }
    ls[threadIdx.x] = s;
    __syncthreads();
    for (int off = 128; off > 0; off >>= 1) {
        if (threadIdx.x < off) ls[threadIdx.x] += ls[threadIdx.x + off];
        __syncthreads();
    }
    if (threadIdx.x == 0) bsum[blockIdx.x] = ls[0];
}

__global__ __launch_bounds__(512) void topscan_kernel(int* __restrict__ bsum, int nb) {
    __shared__ int ls[512];
    int t = threadIdx.x;
    int v = (t < nb) ? bsum[t] : 0;
    ls[t] = v;
    __syncthreads();
    for (int off = 1; off < 512; off <<= 1) {
        int x = ls[t];
        if (t >= off) x += ls[t - off];
        __syncthreads();
        ls[t] = x;
        __syncthreads();
    }
    if (t < nb) bsum[t] = ls[t] - v;  // exclusive
}

__global__ __launch_bounds__(256) void blockscan1024_kernel(const unsigned long long* __restrict__ packed,
                                                            const int* __restrict__ bsum,
                                                            int* __restrict__ ptr, int n, int E) {
    __shared__ int ls[256];
    int base = blockIdx.x * 1024 + threadIdx.x * 4;
    int c[4];
    int s = 0;
#pragma unroll
    for (int k = 0; k < 4; k++) {
        int i = base + k;
        c[k] = (i < n) ? (int)(packed[i] & 0xffffffffull) : 0;
        s += c[k];
    }
    ls[threadIdx.x] = s;
    __syncthreads();
    for (int off = 1; off < 256; off <<= 1) {
        int x = ls[threadIdx.x];
        if (threadIdx.x >= off) x += ls[threadIdx.x - off];
        __syncthreads();
        ls[threadIdx.x] = x;
        __syncthreads();
    }
    int run = ls[threadIdx.x] - s + bsum[blockIdx.x];
#pragma unroll
    for (int k = 0; k < 4; k++) {
        int i = base + k;
        if (i < n) ptr[i] = run;
        run += c[k];
    }
    if (blockIdx.x == 0 && threadIdx.x == 0) ptr[n] = E;
}

// atomic-free permute: pos = ptr[c] + rank[e].
// Edge packed to 4 bytes: src (17 bits, [31:15]) | 15-bit float norm (fp32 bits [30:16]).
__global__ __launch_bounds__(256) void permute_kernel(const int* __restrict__ row,
                                                      const int* __restrict__ col,
                                                      const float* __restrict__ w,
                                                      const float* __restrict__ dinv,
                                                      const int* __restrict__ ptr,
                                                      const int* __restrict__ rank,
                                                      unsigned int* __restrict__ edges, int E) {
    int stride = gridDim.x * blockDim.x;
    for (int e = blockIdx.x * blockDim.x + threadIdx.x; e < E; e += stride) {
        int r = row[e], c = col[e];
        int pos = ptr[c] + rank[e];
        float nrm = dinv[r] * w[e] * dinv[c];
        unsigned int nb = __float_as_uint(nrm);
        unsigned int n15 = (nb + 0x8000u) >> 16;        // round-to-nearest, sign-free
        if (n15 > 0x7fffu) n15 = 0x7fffu;
        edges[pos] = ((unsigned int)r << 15) | n15;
    }
}

// ---------------- layer-1 GEMM (K=14, VALU), grouped store ----------------

template <int K>
__global__ __launch_bounds__(256) void gemm_kernel(const float* __restrict__ h,
                                                   const float* __restrict__ W,
                                                   half_t* __restrict__ xw, int n_nodes) {
    int f = threadIdx.x & 63;
    float wcol[K];
#pragma unroll
    for (int k = 0; k < K; k++) wcol[k] = W[k * HID + f];
    half_t* xg = xw + (size_t)(f >> 4) * GSTRIDE + (f & 15);
    int wave = (blockIdx.x * blockDim.x + threadIdx.x) >> 6;
    int nwaves = (gridDim.x * blockDim.x) >> 6;
    for (int n = wave; n < n_nodes; n += nwaves) {
        const float* hr = h + (size_t)n * K;
        float acc = 0.f;
#pragma unroll
        for (int k = 0; k < K; k++) acc += hr[k] * wcol[k];
        xg[(size_t)n * 16] = (half_t)acc;
    }
}

// ---------------- MFMA GEMM with fused BN+ReLU, grouped store ----------------
__global__ __launch_bounds__(256) void gemm_bn_mfma_kernel(const float* __restrict__ h,
                                                           const float* __restrict__ W,
                                                           const float* __restrict__ stats,
                                                           const float* __restrict__ gamma,
                                                           const float* __restrict__ beta,
                                                           half_t* __restrict__ xw, int n_nodes) {
    __shared__ float sc_s[HID], sh_s[HID];
    if (threadIdx.x < 64) {
        float mean = stats[threadIdx.x] * (1.0f / N_NODES);
        float var = stats[64 + threadIdx.x] * (1.0f / N_NODES) - mean * mean;
        float sc = gamma[threadIdx.x] * rsqrtf(var + EPS);
        sc_s[threadIdx.x] = sc;
        sh_s[threadIdx.x] = beta[threadIdx.x] - mean * sc;
    }
    __syncthreads();
    int lane = threadIdx.x & 63;
    int col16 = lane & 15;
    int quad = lane >> 4;

    float scA[2][8], shA[2][8];
#pragma unroll
    for (int kh = 0; kh < 2; kh++)
#pragma unroll
        for (int j = 0; j < 8; j++) {
            int k = kh * 32 + quad * 8 + j;
            scA[kh][j] = sc_s[k];
            shA[kh][j] = sh_s[k];
        }

    half8 bfrag[4][2];
#pragma unroll
    for (int t = 0; t < 4; t++)
#pragma unroll
        for (int kh = 0; kh < 2; kh++)
#pragma unroll
            for (int j = 0; j < 8; j++) {
                int k = kh * 32 + quad * 8 + j;
                bfrag[t][kh][j] = (half_t)W[k * HID + t * 16 + col16];
            }

    int wave = (blockIdx.x * blockDim.x + threadIdx.x) >> 6;
    int nwaves = (gridDim.x * blockDim.x) >> 6;
    int ntiles = n_nodes >> 4;
    for (int tIdx = wave; tIdx < ntiles; tIdx += nwaves) {
        int n0 = tIdx << 4;
        const float* hr = h + (size_t)(n0 + col16) * HID + quad * 8;
        half8 afrag[2];
#pragma unroll
        for (int kh = 0; kh < 2; kh++) {
            float4 p0 = *(const float4*)(hr + kh * 32);
            float4 p1 = *(const float4*)(hr + kh * 32 + 4);
            float fv[8] = {p0.x, p0.y, p0.z, p0.w, p1.x, p1.y, p1.z, p1.w};
#pragma unroll
            for (int j = 0; j < 8; j++) {
                float v = fv[j] * scA[kh][j] + shA[kh][j];
                afrag[kh][j] = (half_t)fmaxf(v, 0.f);
            }
        }
        f32x4 acc[4];
#pragma unroll
        for (int t = 0; t < 4; t++) {
            f32x4 z = {0.f, 0.f, 0.f, 0.f};
            acc[t] = __builtin_amdgcn_mfma_f32_16x16x32_f16(afrag[0], bfrag[t][0], z, 0, 0, 0);
            acc[t] = __builtin_amdgcn_mfma_f32_16x16x32_f16(afrag[1], bfrag[t][1], acc[t], 0, 0, 0);
        }
#pragma unroll
        for (int t = 0; t < 4; t++) {
            half_t* xg = xw + (size_t)t * GSTRIDE;
#pragma unroll
            for (int r = 0; r < 4; r++) {
                int rowi = n0 + quad * 4 + r;
                xg[(size_t)rowi * 16 + col16] = (half_t)acc[t][r];
            }
        }
    }
}

// ---------------- feature-grouped CSR gather (round-5 structure, u32 edges) ----
// Quad of a wave = (node, 16 features); 4 independent node streams per wave.
// One shfl per edge (packed u32), unpack after broadcast. 4-deep gather MLP.
__global__ __launch_bounds__(256) void gather_stats_kernel(const int* __restrict__ ptr,
                                                           const unsigned int* __restrict__ edges,
                                                           const half_t* __restrict__ xw,
                                                           const float* __restrict__ dinv,
                                                           const float* __restrict__ b,
                                                           float* __restrict__ h,
                                                           float* __restrict__ stats,
                                                           int n_nodes) {
    int g = (blockIdx.x & 7) >> 1;                           // feature group 0..3
    int grank = ((blockIdx.x >> 3) << 1) | (blockIdx.x & 1); // rank within group
    int lane16 = threadIdx.x & 15;
    int quadLocal = threadIdx.x >> 4;                        // 0..15
    int quadId = grank * 16 + quadLocal;
    int nquads = (gridDim.x >> 2) * 16;

    const half_t* xg = xw + (size_t)g * GSTRIDE;
    const char* xgb = (const char*)xg + lane16 * 2;
    int f = g * 16 + lane16;
    float bf = b[f];
    int base = ((threadIdx.x & 63) >> 4) * 16;               // quad's shfl window

    float s = 0.f, s2 = 0.f;
    for (int n = quadId; n < n_nodes; n += nquads) {
        int beg = ptr[n];
        int c = ptr[n + 1] - beg;
        float a0 = 0.f, a1 = 0.f, a2 = 0.f, a3 = 0.f;
        for (int j0 = 0; j0 < c; j0 += 16) {
            int m = c - j0;
            if (m > 16) m = 16;
            int ev = 0;
            if (lane16 < m) ev = (int)edges[beg + j0 + lane16];
            int j = 0;
            for (; j + 4 <= m; j += 4) {
                unsigned int u0 = (unsigned int)__shfl(ev, base + j);
                unsigned int u1 = (unsigned int)__shfl(ev, base + j + 1);
                unsigned int u2 = (unsigned int)__shfl(ev, base + j + 2);
                unsigned int u3 = (unsigned int)__shfl(ev, base + j + 3);
                float w0 = __uint_as_float((u0 & 0x7fffu) << 16);
                float w1 = __uint_as_float((u1 & 0x7fffu) << 16);
                float w2 = __uint_as_float((u2 & 0x7fffu) << 16);
                float w3 = __uint_as_float((u3 & 0x7fffu) << 16);
                float x0 = (float)*(const half_t*)(xgb + ((size_t)(u0 >> 15) << 5));
                float x1 = (float)*(const half_t*)(xgb + ((size_t)(u1 >> 15) << 5));
                float x2 = (float)*(const half_t*)(xgb + ((size_t)(u2 >> 15) << 5));
                float x3 = (float)*(const half_t*)(xgb + ((size_t)(u3 >> 15) << 5));
                a0 += w0 * x0; a1 += w1 * x1; a2 += w2 * x2; a3 += w3 * x3;
            }
            if (j < m) {
                unsigned int u = (unsigned int)__shfl(ev, base + j);
                a1 += __uint_as_float((u & 0x7fffu) << 16) *
                      (float)*(const half_t*)(xgb + ((size_t)(u >> 15) << 5));
            }
            if (j + 1 < m) {
                unsigned int u = (unsigned int)__shfl(ev, base + j + 1);
                a2 += __uint_as_float((u & 0x7fffu) << 16) *
                      (float)*(const half_t*)(xgb + ((size_t)(u >> 15) << 5));
            }
            if (j + 2 < m) {
                unsigned int u = (unsigned int)__shfl(ev, base + j + 2);
                a3 += __uint_as_float((u & 0x7fffu) << 16) *
                      (float)*(const half_t*)(xgb + ((size_t)(u >> 15) << 5));
            }
        }
        float di = dinv[n];
        float v = ((a0 + a1) + (a2 + a3)) + di * di * (float)xg[(size_t)n * 16 + lane16] + bf;
        h[(size_t)n * HID + f] = v;
        s += v;
        s2 += v * v;
    }
    __shared__ float ls[256], ls2[256];
    ls[threadIdx.x] = s;
    ls2[threadIdx.x] = s2;
    __syncthreads();
    if (threadIdx.x < 16) {
        float a = 0.f, aa = 0.f;
#pragma unroll
        for (int k = 0; k < 16; k++) {
            a += ls[k * 16 + threadIdx.x];
            aa += ls2[k * 16 + threadIdx.x];
        }
        atomicAdd(&stats[g * 16 + threadIdx.x], a);
        atomicAdd(&stats[64 + g * 16 + threadIdx.x], aa);
    }
}

// ---------------- layer 3: BN + ReLU + write node_embs + segment-sum --------
__global__ __launch_bounds__(256) void bn_relu_seg_kernel(float* __restrict__ h,
                                                          const float* __restrict__ stats,
                                                          const float* __restrict__ gamma,
                                                          const float* __restrict__ beta,
                                                          const int* __restrict__ batch,
                                                          float* __restrict__ gemb,
                                                          int n_nodes) {
    int g = blockIdx.x * blockDim.x + threadIdx.x;
    int f = g & 63;
    int wave = g >> 6;
    int nwaves = (gridDim.x * blockDim.x) >> 6;
    int chunk = (n_nodes + nwaves - 1) / nwaves;
    int n0 = wave * chunk;
    int n1 = n0 + chunk;
    if (n1 > n_nodes) n1 = n_nodes;
    if (n0 >= n_nodes) return;
    float mean = stats[f] * (1.0f / N_NODES);
    float var = stats[64 + f] * (1.0f / N_NODES) - mean * mean;
    float sc = gamma[f] * rsqrtf(var + EPS);
    float sh = beta[f] - mean * sc;
    int curg = batch[n0];
    float racc = 0.f;
    for (int n = n0; n < n1; n++) {
        int bg = batch[n];
        if (bg != curg) {
            atomicAdd(&gemb[(size_t)curg * HID + f], racc);
            racc = 0.f;
            curg = bg;
        }
        size_t idx = (size_t)n * HID + f;
        float v = h[idx] * sc + sh;
        v = fmaxf(v, 0.f);
        h[idx] = v;
        racc += v;
    }
    atomicAdd(&gemb[(size_t)curg * HID + f], racc);
}

__global__ __launch_bounds__(256) void final_kernel(const float* __restrict__ gemb,
                                                    const float* __restrict__ fcW,
                                                    const float* __restrict__ fcb,
                                                    float* __restrict__ out) {
    int g = blockIdx.x * blockDim.x + threadIdx.x;
    if (g >= N_GRAPHS * N_CLS) return;
    int gr = g >> 1, c = g & 1;
    float acc = fcb[c];
#pragma unroll
    for (int k = 0; k < HID; k++) acc += gemb[gr * HID + k] * fcW[k * N_CLS + c];
    out[g] = acc;
}

// ---------------- launch ----------------

extern "C" void kernel_launch(void* const* d_in, const int* in_sizes, int n_in,
                              void* d_out, int out_size, void* d_ws, size_t ws_size,
                              hipStream_t stream) {
    const float* x    = (const float*)d_in[0];
    const int*   ei   = (const int*)d_in[1];
    const int*   batch= (const int*)d_in[2];
    const float* ew   = (const float*)d_in[3];
    const float* W1   = (const float*)d_in[4];
    const float* b1   = (const float*)d_in[5];
    const float* W2   = (const float*)d_in[6];
    const float* b2   = (const float*)d_in[7];
    const float* W3   = (const float*)d_in[8];
    const float* b3   = (const float*)d_in[9];
    const float* g1   = (const float*)d_in[10];
    const float* bt1  = (const float*)d_in[11];
    const float* g2   = (const float*)d_in[12];
    const float* bt2  = (const float*)d_in[13];
    const float* g3   = (const float*)d_in[14];
    const float* bt3  = (const float*)d_in[15];
    const float* fcW  = (const float*)d_in[16];
    const float* fcb  = (const float*)d_in[17];

    const int* row = ei;
    const int* col = ei + N_EDGES;

    // d_out layout: out [2048*2] | node_embs [100000*64] | graph_emb [2048*64]
    float* out_head  = (float*)d_out;
    float* node_embs = out_head + N_GRAPHS * N_CLS;
    float* gemb      = node_embs + (size_t)N_NODES * HID;

    // ws layout
    half_t* xwh  = (half_t*)d_ws;                             // 12.8 MB (4 planes)
    unsigned int* edges = (unsigned int*)(xwh + (size_t)N_NODES * HID); // 6.4 MB
    unsigned long long* packed = (unsigned long long*)(edges + N_EDGES); // 800 KB
    float* dinv  = (float*)(packed + N_NODES);                // 400 KB
    float* stats = dinv + N_NODES;                            // 512 B
    int*   ptr   = (int*)(stats + 128);                       // 400 KB (+1)
    int*   rank  = ptr + N_NODES + 1;                         // 6.4 MB
    int*   bsum  = rank + N_EDGES;                            // 512 B

    const int B   = 256;
    const int gN  = (N_NODES + B - 1) / B;
    const int NBS = (N_NODES + 1023) / 1024;  // 98 scan blocks
    const int gGS = 1024;                     // grid-stride
    const int gGA = 2048;                     // gather (mult of 8)

    // ---- CSR build: 1 packed atomic per edge, atomic-free permute ----
    hipMemsetAsync(packed, 0, N_NODES * sizeof(unsigned long long), stream);
    hist_rank_kernel<<<gGS, B, 0, stream>>>(col, ew, packed, rank, N_EDGES);
    dinv_from_packed<<<gN, B, 0, stream>>>(packed, dinv, N_NODES);
    blocksum1024_kernel<<<NBS, B, 0, stream>>>(packed, bsum, N_NODES);
    topscan_kernel<<<1, 512, 0, stream>>>(bsum, NBS);
    blockscan1024_kernel<<<NBS, B, 0, stream>>>(packed, bsum, ptr, N_NODES, N_EDGES);
    permute_kernel<<<gGS, B, 0, stream>>>(row, col, ew, dinv, ptr, rank, edges, N_EDGES);

    float* h = node_embs;  // raw (pre-BN) activation; ends as h3 output

    // ---- layer 1 ----
    gemm_kernel<IN_F><<<gGS, B, 0, stream>>>(x, W1, xwh, N_NODES);
    hipMemsetAsync(stats, 0, 128 * sizeof(float), stream);
    gather_stats_kernel<<<gGA, B, 0, stream>>>(ptr, edges, xwh, dinv, b1, h, stats, N_NODES);

    // ---- layer 2 (BN1+ReLU fused into MFMA GEMM) ----
    gemm_bn_mfma_kernel<<<gGS, B, 0, stream>>>(h, W2, stats, g1, bt1, xwh, N_NODES);
    hipMemsetAsync(stats, 0, 128 * sizeof(float), stream);
    gather_stats_kernel<<<gGA, B, 0, stream>>>(ptr, edges, xwh, dinv, b2, h, stats, N_NODES);

    // ---- layer 3 (BN2+ReLU fused into MFMA GEMM) ----
    gemm_bn_mfma_kernel<<<gGS, B, 0, stream>>>(h, W3, stats, g2, bt2, xwh, N_NODES);
    hipMemsetAsync(stats, 0, 128 * sizeof(float), stream);
    gather_stats_kernel<<<gGA, B, 0, stream>>>(ptr, edges, xwh, dinv, b3, h, stats, N_NODES);

    // ---- BN3 + ReLU + node_embs + segment-sum ----
    hipMemsetAsync(gemb, 0, (size_t)N_GRAPHS * HID * sizeof(float), stream);
    bn_relu_seg_kernel<<<gGS, B, 0, stream>>>(h, stats, g3, bt3, batch, gemb, N_NODES);

    // ---- readout ----
    final_kernel<<<(N_GRAPHS * N_CLS + B - 1) / B, B, 0, stream>>>(gemb, fcW, fcb, out_head);
}

// Round 8
// 440.384 us; speedup vs baseline: 1.7545x; 1.1216x over previous
//
#include <hip/hip_runtime.h>

#define N_NODES 100000
#define N_EDGES 1600000
#define N_GRAPHS 2048
#define HID 64
#define IN_F 14
#define N_CLS 2
#define EPS 1e-5f

#define BSHIFT 9
#define NBUCK 196                       // ceil(100000 / 512)
#define ABLOCKS 256
#define CHUNK (N_EDGES / ABLOCKS)       // 6250, exact

typedef _Float16 half_t;
typedef _Float16 half8 __attribute__((ext_vector_type(8)));
typedef float f32x4 __attribute__((ext_vector_type(4)));

#define GSTRIDE ((size_t)N_NODES * 16)  // halves per feature-group plane

// ============ CSR build, atomic-free (global) two-level counting sort ========

// A1: per-chunk coarse histogram (196 buckets) via LDS atomics
__global__ __launch_bounds__(256) void histA_kernel(const int* __restrict__ col,
                                                    int* __restrict__ histG) {
    __shared__ int hl[NBUCK];
    for (int i = threadIdx.x; i < NBUCK; i += 256) hl[i] = 0;
    __syncthreads();
    int e0 = blockIdx.x * CHUNK;
    for (int e = e0 + threadIdx.x; e < e0 + CHUNK; e += 256)
        atomicAdd(&hl[col[e] >> BSHIFT], 1);
    __syncthreads();
    for (int i = threadIdx.x; i < NBUCK; i += 256)
        histG[i * ABLOCKS + blockIdx.x] = hl[i];
}

// S1: per-bucket totals (each scan-block = one bucket row of 256)
__global__ __launch_bounds__(256) void scanS1_kernel(const int* __restrict__ histG,
                                                     int* __restrict__ bsumA) {
    __shared__ int ls[256];
    ls[threadIdx.x] = histG[blockIdx.x * 256 + threadIdx.x];
    __syncthreads();
    for (int off = 128; off > 0; off >>= 1) {
        if (threadIdx.x < off) ls[threadIdx.x] += ls[threadIdx.x + off];
        __syncthreads();
    }
    if (threadIdx.x == 0) bsumA[blockIdx.x] = ls[0];
}

// S2: exclusive scan of bucket totals (nb <= 512)
__global__ __launch_bounds__(512) void topscan_kernel(int* __restrict__ bsum, int nb) {
    __shared__ int ls[512];
    int t = threadIdx.x;
    int v = (t < nb) ? bsum[t] : 0;
    ls[t] = v;
    __syncthreads();
    for (int off = 1; off < 512; off <<= 1) {
        int x = ls[t];
        if (t >= off) x += ls[t - off];
        __syncthreads();
        ls[t] = x;
        __syncthreads();
    }
    if (t < nb) bsum[t] = ls[t] - v;  // exclusive: bucket start offsets
}

// S3: per-bucket exclusive scan of its 256 block-entries + bucket base -> flat
// EA offsets; also set ptr[N_NODES] = E once.
__global__ __launch_bounds__(256) void scanS3_kernel(int* __restrict__ histG,
                                                     const int* __restrict__ bsumA,
                                                     int* __restrict__ ptr) {
    __shared__ int ls[256];
    int idx = blockIdx.x * 256 + threadIdx.x;
    int v = histG[idx];
    ls[threadIdx.x] = v;
    __syncthreads();
    for (int off = 1; off < 256; off <<= 1) {
        int x = ls[threadIdx.x];
        if (threadIdx.x >= off) x += ls[threadIdx.x - off];
        __syncthreads();
        ls[threadIdx.x] = x;
        __syncthreads();
    }
    histG[idx] = ls[threadIdx.x] - v + bsumA[blockIdx.x];
    if (blockIdx.x == 0 && threadIdx.x == 0) ptr[N_NODES] = N_EDGES;
}

// A2: scatter edges into bucket-contiguous EA records {src, (w*8192)<<17 | col}
__global__ __launch_bounds__(256) void scatterA_kernel(const int* __restrict__ row,
                                                       const int* __restrict__ col,
                                                       const float* __restrict__ w,
                                                       const int* __restrict__ histG,
                                                       int2* __restrict__ EA) {
    __shared__ int cur[NBUCK];
    for (int i = threadIdx.x; i < NBUCK; i += 256)
        cur[i] = histG[i * ABLOCKS + blockIdx.x];
    __syncthreads();
    int e0 = blockIdx.x * CHUNK;
    for (int e = e0 + threadIdx.x; e < e0 + CHUNK; e += 256) {
        int c = col[e];
        int r = row[e];
        int fx = (int)__float2uint_rn(w[e] * 8192.0f);   // 15-bit fixed, exact for w=1
        int pos = atomicAdd(&cur[c >> BSHIFT], 1);        // LDS atomic
        EA[pos] = make_int2(r, (fx << 17) | c);
    }
}

// B: one block per bucket (512 cols): dense LDS hist+scan -> ptr, dinv; then
// place edges grouped by col into EB.
__global__ __launch_bounds__(256) void bucket_kernel(const int2* __restrict__ EA,
                                                     const int* __restrict__ bsumA,
                                                     int2* __restrict__ EB,
                                                     int* __restrict__ ptr,
                                                     float* __restrict__ dinv) {
    __shared__ int hist[512], wsum[512], cur[512];
    int b = blockIdx.x;
    int beg = bsumA[b];
    int end = (b == NBUCK - 1) ? N_EDGES : bsumA[b + 1];
    int i0 = threadIdx.x, i1 = threadIdx.x + 256;
    hist[i0] = 0; hist[i1] = 0;
    wsum[i0] = 0; wsum[i1] = 0;
    __syncthreads();
    for (int e = beg + threadIdx.x; e < end; e += 256) {
        int2 ed = EA[e];
        int c9 = ed.y & 511;
        atomicAdd(&hist[c9], 1);
        atomicAdd(&wsum[c9], (int)((unsigned int)ed.y >> 17));
    }
    __syncthreads();
    int cnt0 = hist[i0], cnt1 = hist[i1];
    // inclusive Hillis-Steele scan over 512 with 256 threads (2 elems each)
    for (int off = 1; off < 512; off <<= 1) {
        int v0 = hist[i0], v1 = hist[i1];
        int a0 = (i0 >= off) ? hist[i0 - off] : 0;
        int a1 = (i1 >= off) ? hist[i1 - off] : 0;
        __syncthreads();
        hist[i0] = v0 + a0;
        hist[i1] = v1 + a1;
        __syncthreads();
    }
    int excl0 = hist[i0] - cnt0, excl1 = hist[i1] - cnt1;
    cur[i0] = beg + excl0;
    cur[i1] = beg + excl1;
    int col0 = (b << BSHIFT) + i0, col1 = (b << BSHIFT) + i1;
    if (col0 < N_NODES) {
        ptr[col0] = beg + excl0;
        dinv[col0] = rsqrtf(1.0f + (float)wsum[i0] * (1.0f / 8192.0f));
    }
    if (col1 < N_NODES) {
        ptr[col1] = beg + excl1;
        dinv[col1] = rsqrtf(1.0f + (float)wsum[i1] * (1.0f / 8192.0f));
    }
    __syncthreads();
    for (int e = beg + threadIdx.x; e < end; e += 256) {
        int2 ed = EA[e];
        int pos = atomicAdd(&cur[ed.y & 511], 1);         // LDS atomic
        EB[pos] = ed;
    }
}

// C: finalize packed u32 edges: src (17b) | 15-bit float norm (fp32 bits [30:16])
__global__ __launch_bounds__(256) void finalize_kernel(const int2* __restrict__ EB,
                                                       const float* __restrict__ dinv,
                                                       unsigned int* __restrict__ edges, int E) {
    int stride = gridDim.x * blockDim.x;
    for (int e = blockIdx.x * blockDim.x + threadIdx.x; e < E; e += stride) {
        int2 ed = EB[e];
        int c = ed.y & 0x1ffff;
        float w = (float)((unsigned int)ed.y >> 17) * (1.0f / 8192.0f);
        float nrm = dinv[ed.x] * w * dinv[c];
        unsigned int nb = __float_as_uint(nrm);
        unsigned int n15 = (nb + 0x8000u) >> 16;
        if (n15 > 0x7fffu) n15 = 0x7fffu;
        edges[e] = ((unsigned int)ed.x << 15) | n15;
    }
}

// ---------------- layer-1 GEMM (K=14, VALU), grouped store ----------------

template <int K>
__global__ __launch_bounds__(256) void gemm_kernel(const float* __restrict__ h,
                                                   const float* __restrict__ W,
                                                   half_t* __restrict__ xw, int n_nodes) {
    int f = threadIdx.x & 63;
    float wcol[K];
#pragma unroll
    for (int k = 0; k < K; k++) wcol[k] = W[k * HID + f];
    half_t* xg = xw + (size_t)(f >> 4) * GSTRIDE + (f & 15);
    int wave = (blockIdx.x * blockDim.x + threadIdx.x) >> 6;
    int nwaves = (gridDim.x * blockDim.x) >> 6;
    for (int n = wave; n < n_nodes; n += nwaves) {
        const float* hr = h + (size_t)n * K;
        float acc = 0.f;
#pragma unroll
        for (int k = 0; k < K; k++) acc += hr[k] * wcol[k];
        xg[(size_t)n * 16] = (half_t)acc;
    }
}

// ---------------- MFMA GEMM with fused BN+ReLU, grouped store ----------------
__global__ __launch_bounds__(256) void gemm_bn_mfma_kernel(const float* __restrict__ h,
                                                           const float* __restrict__ W,
                                                           const float* __restrict__ stats,
                                                           const float* __restrict__ gamma,
                                                           const float* __restrict__ beta,
                                                           half_t* __restrict__ xw, int n_nodes) {
    __shared__ float sc_s[HID], sh_s[HID];
    if (threadIdx.x < 64) {
        float mean = stats[threadIdx.x] * (1.0f / N_NODES);
        float var = stats[64 + threadIdx.x] * (1.0f / N_NODES) - mean * mean;
        float sc = gamma[threadIdx.x] * rsqrtf(var + EPS);
        sc_s[threadIdx.x] = sc;
        sh_s[threadIdx.x] = beta[threadIdx.x] - mean * sc;
    }
    __syncthreads();
    int lane = threadIdx.x & 63;
    int col16 = lane & 15;
    int quad = lane >> 4;

    float scA[2][8], shA[2][8];
#pragma unroll
    for (int kh = 0; kh < 2; kh++)
#pragma unroll
        for (int j = 0; j < 8; j++) {
            int k = kh * 32 + quad * 8 + j;
            scA[kh][j] = sc_s[k];
            shA[kh][j] = sh_s[k];
        }

    half8 bfrag[4][2];
#pragma unroll
    for (int t = 0; t < 4; t++)
#pragma unroll
        for (int kh = 0; kh < 2; kh++)
#pragma unroll
            for (int j = 0; j < 8; j++) {
                int k = kh * 32 + quad * 8 + j;
                bfrag[t][kh][j] = (half_t)W[k * HID + t * 16 + col16];
            }

    int wave = (blockIdx.x * blockDim.x + threadIdx.x) >> 6;
    int nwaves = (gridDim.x * blockDim.x) >> 6;
    int ntiles = n_nodes >> 4;
    for (int tIdx = wave; tIdx < ntiles; tIdx += nwaves) {
        int n0 = tIdx << 4;
        const float* hr = h + (size_t)(n0 + col16) * HID + quad * 8;
        half8 afrag[2];
#pragma unroll
        for (int kh = 0; kh < 2; kh++) {
            float4 p0 = *(const float4*)(hr + kh * 32);
            float4 p1 = *(const float4*)(hr + kh * 32 + 4);
            float fv[8] = {p0.x, p0.y, p0.z, p0.w, p1.x, p1.y, p1.z, p1.w};
#pragma unroll
            for (int j = 0; j < 8; j++) {
                float v = fv[j] * scA[kh][j] + shA[kh][j];
                afrag[kh][j] = (half_t)fmaxf(v, 0.f);
            }
        }
        f32x4 acc[4];
#pragma unroll
        for (int t = 0; t < 4; t++) {
            f32x4 z = {0.f, 0.f, 0.f, 0.f};
            acc[t] = __builtin_amdgcn_mfma_f32_16x16x32_f16(afrag[0], bfrag[t][0], z, 0, 0, 0);
            acc[t] = __builtin_amdgcn_mfma_f32_16x16x32_f16(afrag[1], bfrag[t][1], acc[t], 0, 0, 0);
        }
#pragma unroll
        for (int t = 0; t < 4; t++) {
            half_t* xg = xw + (size_t)t * GSTRIDE;
#pragma unroll
            for (int r = 0; r < 4; r++) {
                int rowi = n0 + quad * 4 + r;
                xg[(size_t)rowi * 16 + col16] = (half_t)acc[t][r];
            }
        }
    }
}

// ---------------- feature-grouped CSR gather (quad per node, u32 edges) ------
__global__ __launch_bounds__(256) void gather_stats_kernel(const int* __restrict__ ptr,
                                                           const unsigned int* __restrict__ edges,
                                                           const half_t* __restrict__ xw,
                                                           const float* __restrict__ dinv,
                                                           const float* __restrict__ b,
                                                           float* __restrict__ h,
                                                           float* __restrict__ stats,
                                                           int n_nodes) {
    int g = (blockIdx.x & 7) >> 1;                           // feature group 0..3
    int grank = ((blockIdx.x >> 3) << 1) | (blockIdx.x & 1); // rank within group
    int lane16 = threadIdx.x & 15;
    int quadLocal = threadIdx.x >> 4;                        // 0..15
    int quadId = grank * 16 + quadLocal;
    int nquads = (gridDim.x >> 2) * 16;

    const half_t* xg = xw + (size_t)g * GSTRIDE;
    const char* xgb = (const char*)xg + lane16 * 2;
    int f = g * 16 + lane16;
    float bf = b[f];
    int base = ((threadIdx.x & 63) >> 4) * 16;               // quad's shfl window

    float s = 0.f, s2 = 0.f;
    for (int n = quadId; n < n_nodes; n += nquads) {
        int beg = ptr[n];
        int c = ptr[n + 1] - beg;
        float a0 = 0.f, a1 = 0.f, a2 = 0.f, a3 = 0.f;
        for (int j0 = 0; j0 < c; j0 += 16) {
            int m = c - j0;
            if (m > 16) m = 16;
            int ev = 0;
            if (lane16 < m) ev = (int)edges[beg + j0 + lane16];
            int j = 0;
            for (; j + 4 <= m; j += 4) {
                unsigned int u0 = (unsigned int)__shfl(ev, base + j);
                unsigned int u1 = (unsigned int)__shfl(ev, base + j + 1);
                unsigned int u2 = (unsigned int)__shfl(ev, base + j + 2);
                unsigned int u3 = (unsigned int)__shfl(ev, base + j + 3);
                float w0 = __uint_as_float((u0 & 0x7fffu) << 16);
                float w1 = __uint_as_float((u1 & 0x7fffu) << 16);
                float w2 = __uint_as_float((u2 & 0x7fffu) << 16);
                float w3 = __uint_as_float((u3 & 0x7fffu) << 16);
                float x0 = (float)*(const half_t*)(xgb + ((size_t)(u0 >> 15) << 5));
                float x1 = (float)*(const half_t*)(xgb + ((size_t)(u1 >> 15) << 5));
                float x2 = (float)*(const half_t*)(xgb + ((size_t)(u2 >> 15) << 5));
                float x3 = (float)*(const half_t*)(xgb + ((size_t)(u3 >> 15) << 5));
                a0 += w0 * x0; a1 += w1 * x1; a2 += w2 * x2; a3 += w3 * x3;
            }
            if (j < m) {
                unsigned int u = (unsigned int)__shfl(ev, base + j);
                a1 += __uint_as_float((u & 0x7fffu) << 16) *
                      (float)*(const half_t*)(xgb + ((size_t)(u >> 15) << 5));
            }
            if (j + 1 < m) {
                unsigned int u = (unsigned int)__shfl(ev, base + j + 1);
                a2 += __uint_as_float((u & 0x7fffu) << 16) *
                      (float)*(const half_t*)(xgb + ((size_t)(u >> 15) << 5));
            }
            if (j + 2 < m) {
                unsigned int u = (unsigned int)__shfl(ev, base + j + 2);
                a3 += __uint_as_float((u & 0x7fffu) << 16) *
                      (float)*(const half_t*)(xgb + ((size_t)(u >> 15) << 5));
            }
        }
        float di = dinv[n];
        float v = ((a0 + a1) + (a2 + a3)) + di * di * (float)xg[(size_t)n * 16 + lane16] + bf;
        h[(size_t)n * HID + f] = v;
        s += v;
        s2 += v * v;
    }
    __shared__ float ls[256], ls2[256];
    ls[threadIdx.x] = s;
    ls2[threadIdx.x] = s2;
    __syncthreads();
    if (threadIdx.x < 16) {
        float a = 0.f, aa = 0.f;
#pragma unroll
        for (int k = 0; k < 16; k++) {
            a += ls[k * 16 + threadIdx.x];
            aa += ls2[k * 16 + threadIdx.x];
        }
        atomicAdd(&stats[g * 16 + threadIdx.x], a);
        atomicAdd(&stats[64 + g * 16 + threadIdx.x], aa);
    }
}

// ---------------- layer 3: BN + ReLU + write node_embs + segment-sum --------
__global__ __launch_bounds__(256) void bn_relu_seg_kernel(float* __restrict__ h,
                                                          const float* __restrict__ stats,
                                                          const float* __restrict__ gamma,
                                                          const float* __restrict__ beta,
                                                          const int* __restrict__ batch,
                                                          float* __restrict__ gemb,
                                                          int n_nodes) {
    int g = blockIdx.x * blockDim.x + threadIdx.x;
    int f = g & 63;
    int wave = g >> 6;
    int nwaves = (gridDim.x * blockDim.x) >> 6;
    int chunk = (n_nodes + nwaves - 1) / nwaves;
    int n0 = wave * chunk;
    int n1 = n0 + chunk;
    if (n1 > n_nodes) n1 = n_nodes;
    if (n0 >= n_nodes) return;
    float mean = stats[f] * (1.0f / N_NODES);
    float var = stats[64 + f] * (1.0f / N_NODES) - mean * mean;
    float sc = gamma[f] * rsqrtf(var + EPS);
    float sh = beta[f] - mean * sc;
    int curg = batch[n0];
    float racc = 0.f;
    for (int n = n0; n < n1; n++) {
        int bg = batch[n];
        if (bg != curg) {
            atomicAdd(&gemb[(size_t)curg * HID + f], racc);
            racc = 0.f;
            curg = bg;
        }
        size_t idx = (size_t)n * HID + f;
        float v = h[idx] * sc + sh;
        v = fmaxf(v, 0.f);
        h[idx] = v;
        racc += v;
    }
    atomicAdd(&gemb[(size_t)curg * HID + f], racc);
}

__global__ __launch_bounds__(256) void final_kernel(const float* __restrict__ gemb,
                                                    const float* __restrict__ fcW,
                                                    const float* __restrict__ fcb,
                                                    float* __restrict__ out) {
    int g = blockIdx.x * blockDim.x + threadIdx.x;
    if (g >= N_GRAPHS * N_CLS) return;
    int gr = g >> 1, c = g & 1;
    float acc = fcb[c];
#pragma unroll
    for (int k = 0; k < HID; k++) acc += gemb[gr * HID + k] * fcW[k * N_CLS + c];
    out[g] = acc;
}

// ---------------- launch ----------------

extern "C" void kernel_launch(void* const* d_in, const int* in_sizes, int n_in,
                              void* d_out, int out_size, void* d_ws, size_t ws_size,
                              hipStream_t stream) {
    const float* x    = (const float*)d_in[0];
    const int*   ei   = (const int*)d_in[1];
    const int*   batch= (const int*)d_in[2];
    const float* ew   = (const float*)d_in[3];
    const float* W1   = (const float*)d_in[4];
    const float* b1   = (const float*)d_in[5];
    const float* W2   = (const float*)d_in[6];
    const float* b2   = (const float*)d_in[7];
    const float* W3   = (const float*)d_in[8];
    const float* b3   = (const float*)d_in[9];
    const float* g1   = (const float*)d_in[10];
    const float* bt1  = (const float*)d_in[11];
    const float* g2   = (const float*)d_in[12];
    const float* bt2  = (const float*)d_in[13];
    const float* g3   = (const float*)d_in[14];
    const float* bt3  = (const float*)d_in[15];
    const float* fcW  = (const float*)d_in[16];
    const float* fcb  = (const float*)d_in[17];

    const int* row = ei;
    const int* col = ei + N_EDGES;

    // d_out layout: out [2048*2] | node_embs [100000*64] | graph_emb [2048*64]
    float* out_head  = (float*)d_out;
    float* node_embs = out_head + N_GRAPHS * N_CLS;
    float* gemb      = node_embs + (size_t)N_NODES * HID;

    // ws layout with lifetime overlays:
    //  R0 (12.8 MB): EB (CSR build) -> xwh (layers; written after EB is dead)
    //  R1 (12.8 MB): EA (phase A) -> final u32 edges (written by finalize, EA dead)
    char* base = (char*)d_ws;
    half_t* xwh = (half_t*)base;                      // R0 as xw planes
    int2*   EB  = (int2*)base;                        // R0 as grouped records
    char* r1 = base + (size_t)N_NODES * HID * 2;      // 12.8e6 B (8-aligned)
    int2*   EA  = (int2*)r1;                          // R1 as phase-A records
    unsigned int* edges = (unsigned int*)r1;          // R1 as final packed edges
    char* r2 = r1 + (size_t)N_EDGES * 8;
    float* dinv  = (float*)r2;                        // 400 KB
    float* stats = dinv + N_NODES;                    // 512 B
    int*   ptr   = (int*)(stats + 128);               // (N_NODES+1) ints
    int*   histG = ptr + N_NODES + 1;                 // NBUCK*ABLOCKS ints (200 KB)
    int*   bsumA = histG + NBUCK * ABLOCKS;           // NBUCK ints

    const int B   = 256;
    const int gGS = 1024;   // grid-stride
    const int gGA = 2048;   // gather (mult of 8)

    // ---- CSR build: LDS counting sort, zero global atomics ----
    histA_kernel<<<ABLOCKS, B, 0, stream>>>(col, histG);
    scanS1_kernel<<<NBUCK, B, 0, stream>>>(histG, bsumA);
    topscan_kernel<<<1, 512, 0, stream>>>(bsumA, NBUCK);
    scanS3_kernel<<<NBUCK, B, 0, stream>>>(histG, bsumA, ptr);
    scatterA_kernel<<<ABLOCKS, B, 0, stream>>>(row, col, ew, histG, EA);
    bucket_kernel<<<NBUCK, B, 0, stream>>>(EA, bsumA, EB, ptr, dinv);
    finalize_kernel<<<gGS, B, 0, stream>>>(EB, dinv, edges, N_EDGES);

    float* h = node_embs;  // raw (pre-BN) activation; ends as h3 output

    // ---- layer 1 (xwh overwrites EB region — EB dead after finalize) ----
    gemm_kernel<IN_F><<<gGS, B, 0, stream>>>(x, W1, xwh, N_NODES);
    hipMemsetAsync(stats, 0, 128 * sizeof(float), stream);
    gather_stats_kernel<<<gGA, B, 0, stream>>>(ptr, edges, xwh, dinv, b1, h, stats, N_NODES);

    // ---- layer 2 (BN1+ReLU fused into MFMA GEMM) ----
    gemm_bn_mfma_kernel<<<gGS, B, 0, stream>>>(h, W2, stats, g1, bt1, xwh, N_NODES);
    hipMemsetAsync(stats, 0, 128 * sizeof(float), stream);
    gather_stats_kernel<<<gGA, B, 0, stream>>>(ptr, edges, xwh, dinv, b2, h, stats, N_NODES);

    // ---- layer 3 (BN2+ReLU fused into MFMA GEMM) ----
    gemm_bn_mfma_kernel<<<gGS, B, 0, stream>>>(h, W3, stats, g2, bt2, xwh, N_NODES);
    hipMemsetAsync(stats, 0, 128 * sizeof(float), stream);
    gather_stats_kernel<<<gGA, B, 0, stream>>>(ptr, edges, xwh, dinv, b3, h, stats, N_NODES);

    // ---- BN3 + ReLU + node_embs + segment-sum ----
    hipMemsetAsync(gemb, 0, (size_t)N_GRAPHS * HID * sizeof(float), stream);
    bn_relu_seg_kernel<<<gGS, B, 0, stream>>>(h, stats, g3, bt3, batch, gemb, N_NODES);

    // ---- readout ----
    final_kernel<<<(N_GRAPHS * N_CLS + B - 1) / B, B, 0, stream>>>(gemb, fcW, fcb, out_head);
}

// Round 9
// 418.446 us; speedup vs baseline: 1.8465x; 1.0524x over previous
//
#include <hip/hip_runtime.h>

#define N_NODES 100000
#define N_EDGES 1600000
#define N_GRAPHS 2048
#define HID 64
#define IN_F 14
#define N_CLS 2
#define EPS 1e-5f

#define BSHIFT 9
#define NBUCK 196                       // ceil(100000 / 512)
#define ABLOCKS 256
#define CHUNK (N_EDGES / ABLOCKS)       // 6250, exact

#define NBLK2 128                       // node-sort blocks
#define NCHUNK2 ((N_NODES + NBLK2 - 1) / NBLK2)  // 782

typedef _Float16 half_t;
typedef _Float16 half8 __attribute__((ext_vector_type(8)));
typedef float f32x4 __attribute__((ext_vector_type(4)));

#define GSTRIDE ((size_t)N_NODES * 16)  // halves per feature-group plane

// ============ CSR build, atomic-free (global) two-level counting sort ========

__global__ __launch_bounds__(256) void histA_kernel(const int* __restrict__ col,
                                                    int* __restrict__ histG) {
    __shared__ int hl[NBUCK];
    for (int i = threadIdx.x; i < NBUCK; i += 256) hl[i] = 0;
    __syncthreads();
    int e0 = blockIdx.x * CHUNK;
    for (int e = e0 + threadIdx.x; e < e0 + CHUNK; e += 256)
        atomicAdd(&hl[col[e] >> BSHIFT], 1);
    __syncthreads();
    for (int i = threadIdx.x; i < NBUCK; i += 256)
        histG[i * ABLOCKS + blockIdx.x] = hl[i];
}

__global__ __launch_bounds__(256) void scanS1_kernel(const int* __restrict__ histG,
                                                     int* __restrict__ bsumA) {
    __shared__ int ls[256];
    ls[threadIdx.x] = histG[blockIdx.x * 256 + threadIdx.x];
    __syncthreads();
    for (int off = 128; off > 0; off >>= 1) {
        if (threadIdx.x < off) ls[threadIdx.x] += ls[threadIdx.x + off];
        __syncthreads();
    }
    if (threadIdx.x == 0) bsumA[blockIdx.x] = ls[0];
}

__global__ __launch_bounds__(512) void topscan_kernel(int* __restrict__ bsum, int nb) {
    __shared__ int ls[512];
    int t = threadIdx.x;
    int v = (t < nb) ? bsum[t] : 0;
    ls[t] = v;
    __syncthreads();
    for (int off = 1; off < 512; off <<= 1) {
        int x = ls[t];
        if (t >= off) x += ls[t - off];
        __syncthreads();
        ls[t] = x;
        __syncthreads();
    }
    if (t < nb) bsum[t] = ls[t] - v;  // exclusive
}

__global__ __launch_bounds__(256) void scanS3_kernel(int* __restrict__ histG,
                                                     const int* __restrict__ bsumA,
                                                     int* __restrict__ ptr) {
    __shared__ int ls[256];
    int idx = blockIdx.x * 256 + threadIdx.x;
    int v = histG[idx];
    ls[threadIdx.x] = v;
    __syncthreads();
    for (int off = 1; off < 256; off <<= 1) {
        int x = ls[threadIdx.x];
        if (threadIdx.x >= off) x += ls[threadIdx.x - off];
        __syncthreads();
        ls[threadIdx.x] = x;
        __syncthreads();
    }
    histG[idx] = ls[threadIdx.x] - v + bsumA[blockIdx.x];
    if (blockIdx.x == 0 && threadIdx.x == 0) ptr[N_NODES] = N_EDGES;
}

__global__ __launch_bounds__(256) void scatterA_kernel(const int* __restrict__ row,
                                                       const int* __restrict__ col,
                                                       const float* __restrict__ w,
                                                       const int* __restrict__ histG,
                                                       int2* __restrict__ EA) {
    __shared__ int cur[NBUCK];
    for (int i = threadIdx.x; i < NBUCK; i += 256)
        cur[i] = histG[i * ABLOCKS + blockIdx.x];
    __syncthreads();
    int e0 = blockIdx.x * CHUNK;
    for (int e = e0 + threadIdx.x; e < e0 + CHUNK; e += 256) {
        int c = col[e];
        int r = row[e];
        int fx = (int)__float2uint_rn(w[e] * 8192.0f);   // 15-bit fixed, exact for w=1
        int pos = atomicAdd(&cur[c >> BSHIFT], 1);        // LDS atomic
        EA[pos] = make_int2(r, (fx << 17) | c);
    }
}

__global__ __launch_bounds__(256) void bucket_kernel(const int2* __restrict__ EA,
                                                     const int* __restrict__ bsumA,
                                                     int2* __restrict__ EB,
                                                     int* __restrict__ ptr,
                                                     float* __restrict__ dinv) {
    __shared__ int hist[512], wsum[512], cur[512];
    int b = blockIdx.x;
    int beg = bsumA[b];
    int end = (b == NBUCK - 1) ? N_EDGES : bsumA[b + 1];
    int i0 = threadIdx.x, i1 = threadIdx.x + 256;
    hist[i0] = 0; hist[i1] = 0;
    wsum[i0] = 0; wsum[i1] = 0;
    __syncthreads();
    for (int e = beg + threadIdx.x; e < end; e += 256) {
        int2 ed = EA[e];
        int c9 = ed.y & 511;
        atomicAdd(&hist[c9], 1);
        atomicAdd(&wsum[c9], (int)((unsigned int)ed.y >> 17));
    }
    __syncthreads();
    int cnt0 = hist[i0], cnt1 = hist[i1];
    for (int off = 1; off < 512; off <<= 1) {
        int v0 = hist[i0], v1 = hist[i1];
        int a0 = (i0 >= off) ? hist[i0 - off] : 0;
        int a1 = (i1 >= off) ? hist[i1 - off] : 0;
        __syncthreads();
        hist[i0] = v0 + a0;
        hist[i1] = v1 + a1;
        __syncthreads();
    }
    int excl0 = hist[i0] - cnt0, excl1 = hist[i1] - cnt1;
    cur[i0] = beg + excl0;
    cur[i1] = beg + excl1;
    int col0 = (b << BSHIFT) + i0, col1 = (b << BSHIFT) + i1;
    if (col0 < N_NODES) {
        ptr[col0] = beg + excl0;
        dinv[col0] = rsqrtf(1.0f + (float)wsum[i0] * (1.0f / 8192.0f));
    }
    if (col1 < N_NODES) {
        ptr[col1] = beg + excl1;
        dinv[col1] = rsqrtf(1.0f + (float)wsum[i1] * (1.0f / 8192.0f));
    }
    __syncthreads();
    for (int e = beg + threadIdx.x; e < end; e += 256) {
        int2 ed = EA[e];
        int pos = atomicAdd(&cur[ed.y & 511], 1);         // LDS atomic
        EB[pos] = ed;
    }
}

// ============ node degree sort: perm (sorted->orig), ptrS, newbase ===========

// D1: per-block degree histogram, 256 bins, 8-way copy spread
__global__ __launch_bounds__(256) void histD_kernel(const int* __restrict__ ptr,
                                                    int* __restrict__ histD) {
    __shared__ int hl[2048];
    for (int i = threadIdx.x; i < 2048; i += 256) hl[i] = 0;
    __syncthreads();
    int n0 = blockIdx.x * NCHUNK2;
    int n1 = n0 + NCHUNK2; if (n1 > N_NODES) n1 = N_NODES;
    for (int n = n0 + threadIdx.x; n < n1; n += 256) {
        int d = ptr[n + 1] - ptr[n];
        if (d > 255) d = 255;
        atomicAdd(&hl[((threadIdx.x & 7) << 8) + d], 1);
    }
    __syncthreads();
    int s = 0;
#pragma unroll
    for (int c = 0; c < 8; c++) s += hl[(c << 8) + threadIdx.x];
    histD[threadIdx.x * NBLK2 + blockIdx.x] = s;
}

// D2: per-bin row totals
__global__ __launch_bounds__(128) void scanD1_kernel(const int* __restrict__ histD,
                                                     int* __restrict__ rowTot) {
    __shared__ int ls[128];
    ls[threadIdx.x] = histD[blockIdx.x * NBLK2 + threadIdx.x];
    __syncthreads();
    for (int off = 64; off > 0; off >>= 1) {
        if (threadIdx.x < off) ls[threadIdx.x] += ls[threadIdx.x + off];
        __syncthreads();
    }
    if (threadIdx.x == 0) rowTot[blockIdx.x] = ls[0];
}

// D3: global exclusive scans over 256 bins: node counts AND edge counts
__global__ __launch_bounds__(256) void topscanD_kernel(const int* __restrict__ rowTot,
                                                       int* __restrict__ nodeExcl,
                                                       int* __restrict__ edgeExcl,
                                                       int* __restrict__ ptrS) {
    __shared__ int a[256], b[256];
    int t = threadIdx.x;
    int cnt = rowTot[t];
    int ec = cnt * t;
    a[t] = cnt; b[t] = ec;
    __syncthreads();
    for (int off = 1; off < 256; off <<= 1) {
        int va = a[t], vb = b[t];
        if (t >= off) { va += a[t - off]; vb += b[t - off]; }
        __syncthreads();
        a[t] = va; b[t] = vb;
        __syncthreads();
    }
    nodeExcl[t] = a[t] - cnt;
    edgeExcl[t] = b[t] - ec;
    if (t == 0) ptrS[N_NODES] = N_EDGES;
}

// D4: per-row exclusive scan + bin base -> per-(bin,block) start positions
__global__ __launch_bounds__(128) void scanD3_kernel(int* __restrict__ histD,
                                                     const int* __restrict__ nodeExcl) {
    __shared__ int ls[128];
    int idx = blockIdx.x * NBLK2 + threadIdx.x;
    int v = histD[idx];
    ls[threadIdx.x] = v;
    __syncthreads();
    for (int off = 1; off < 128; off <<= 1) {
        int x = ls[threadIdx.x];
        if (threadIdx.x >= off) x += ls[threadIdx.x - off];
        __syncthreads();
        ls[threadIdx.x] = x;
        __syncthreads();
    }
    histD[idx] = ls[threadIdx.x] - v + nodeExcl[blockIdx.x];
}

// D5: scatter nodes into degree-sorted order; emit ptrS + newbase
__global__ __launch_bounds__(256) void scatterD_kernel(const int* __restrict__ ptr,
                                                       const int* __restrict__ histD,
                                                       const int* __restrict__ nodeExcl,
                                                       const int* __restrict__ edgeExcl,
                                                       int* __restrict__ perm,
                                                       int* __restrict__ ptrS,
                                                       int* __restrict__ newbase) {
    __shared__ int cur[256];
    cur[threadIdx.x] = histD[threadIdx.x * NBLK2 + blockIdx.x];
    __syncthreads();
    int n0 = blockIdx.x * NCHUNK2;
    int n1 = n0 + NCHUNK2; if (n1 > N_NODES) n1 = N_NODES;
    for (int n = n0 + threadIdx.x; n < n1; n += 256) {
        int d = ptr[n + 1] - ptr[n];
        if (d > 255) d = 255;
        int pos = atomicAdd(&cur[d], 1);                  // LDS atomic
        int ebase = edgeExcl[d] + (pos - nodeExcl[d]) * d;
        perm[pos] = n;
        ptrS[pos] = ebase;
        newbase[n] = ebase;
    }
}

// C: finalize packed u32 edges into degree-sorted positions:
// src (17b, [31:15]) | 15-bit float norm (fp32 bits [30:16])
__global__ __launch_bounds__(256) void finalize_kernel(const int2* __restrict__ EB,
                                                       const float* __restrict__ dinv,
                                                       const int* __restrict__ ptr,
                                                       const int* __restrict__ newbase,
                                                       unsigned int* __restrict__ edges, int E) {
    int stride = gridDim.x * blockDim.x;
    for (int e = blockIdx.x * blockDim.x + threadIdx.x; e < E; e += stride) {
        int2 ed = EB[e];
        int c = ed.y & 0x1ffff;
        float w = (float)((unsigned int)ed.y >> 17) * (1.0f / 8192.0f);
        float nrm = dinv[ed.x] * w * dinv[c];
        unsigned int nb = __float_as_uint(nrm);
        unsigned int n15 = (nb + 0x8000u) >> 16;
        if (n15 > 0x7fffu) n15 = 0x7fffu;
        int newpos = newbase[c] + (e - ptr[c]);
        edges[newpos] = ((unsigned int)ed.x << 15) | n15;
    }
}

// ---------------- layer-1 GEMM (K=14, VALU), grouped store ----------------

template <int K>
__global__ __launch_bounds__(256) void gemm_kernel(const float* __restrict__ h,
                                                   const float* __restrict__ W,
                                                   half_t* __restrict__ xw, int n_nodes) {
    int f = threadIdx.x & 63;
    float wcol[K];
#pragma unroll
    for (int k = 0; k < K; k++) wcol[k] = W[k * HID + f];
    half_t* xg = xw + (size_t)(f >> 4) * GSTRIDE + (f & 15);
    int wave = (blockIdx.x * blockDim.x + threadIdx.x) >> 6;
    int nwaves = (gridDim.x * blockDim.x) >> 6;
    for (int n = wave; n < n_nodes; n += nwaves) {
        const float* hr = h + (size_t)n * K;
        float acc = 0.f;
#pragma unroll
        for (int k = 0; k < K; k++) acc += hr[k] * wcol[k];
        xg[(size_t)n * 16] = (half_t)acc;
    }
}

// ------- MFMA GEMM: input = fp16 h PLANES, fused BN+ReLU, grouped store ------
__global__ __launch_bounds__(256) void gemm_bn_mfma_kernel(const half_t* __restrict__ h,
                                                           const float* __restrict__ W,
                                                           const float* __restrict__ stats,
                                                           const float* __restrict__ gamma,
                                                           const float* __restrict__ beta,
                                                           half_t* __restrict__ xw, int n_nodes) {
    __shared__ float sc_s[HID], sh_s[HID];
    if (threadIdx.x < 64) {
        float mean = stats[threadIdx.x] * (1.0f / N_NODES);
        float var = stats[64 + threadIdx.x] * (1.0f / N_NODES) - mean * mean;
        float sc = gamma[threadIdx.x] * rsqrtf(var + EPS);
        sc_s[threadIdx.x] = sc;
        sh_s[threadIdx.x] = beta[threadIdx.x] - mean * sc;
    }
    __syncthreads();
    int lane = threadIdx.x & 63;
    int col16 = lane & 15;
    int quad = lane >> 4;

    float scA[2][8], shA[2][8];
#pragma unroll
    for (int kh = 0; kh < 2; kh++)
#pragma unroll
        for (int j = 0; j < 8; j++) {
            int k = kh * 32 + quad * 8 + j;
            scA[kh][j] = sc_s[k];
            shA[kh][j] = sh_s[k];
        }

    half8 bfrag[4][2];
#pragma unroll
    for (int t = 0; t < 4; t++)
#pragma unroll
        for (int kh = 0; kh < 2; kh++)
#pragma unroll
            for (int j = 0; j < 8; j++) {
                int k = kh * 32 + quad * 8 + j;
                bfrag[t][kh][j] = (half_t)W[k * HID + t * 16 + col16];
            }

    int wave = (blockIdx.x * blockDim.x + threadIdx.x) >> 6;
    int nwaves = (gridDim.x * blockDim.x) >> 6;
    int ntiles = n_nodes >> 4;
    for (int tIdx = wave; tIdx < ntiles; tIdx += nwaves) {
        int n0 = tIdx << 4;
        half8 afrag[2];
#pragma unroll
        for (int kh = 0; kh < 2; kh++) {
            int k0 = kh * 32 + quad * 8;
            const half_t* hp = h + (size_t)(k0 >> 4) * GSTRIDE
                                 + (size_t)(n0 + col16) * 16 + (k0 & 15);
            half8 raw = *(const half8*)hp;
#pragma unroll
            for (int j = 0; j < 8; j++) {
                float v = (float)raw[j] * scA[kh][j] + shA[kh][j];
                afrag[kh][j] = (half_t)fmaxf(v, 0.f);
            }
        }
        f32x4 acc[4];
#pragma unroll
        for (int t = 0; t < 4; t++) {
            f32x4 z = {0.f, 0.f, 0.f, 0.f};
            acc[t] = __builtin_amdgcn_mfma_f32_16x16x32_f16(afrag[0], bfrag[t][0], z, 0, 0, 0);
            acc[t] = __builtin_amdgcn_mfma_f32_16x16x32_f16(afrag[1], bfrag[t][1], acc[t], 0, 0, 0);
        }
#pragma unroll
        for (int t = 0; t < 4; t++) {
            half_t* xg = xw + (size_t)t * GSTRIDE;
#pragma unroll
            for (int r = 0; r < 4; r++) {
                int rowi = n0 + quad * 4 + r;
                xg[(size_t)rowi * 16 + col16] = (half_t)acc[t][r];
            }
        }
    }
}

// ------- feature-grouped CSR gather (quad per sorted node, u32 edges) --------
// Degree-sorted node order: the 4 quads of a wave get consecutive sorted nodes
// -> near-identical degrees -> uniform trip counts, minimal mask divergence.
template <bool LAST>
__global__ __launch_bounds__(256) void gather_stats_kernel(const int* __restrict__ ptrS,
                                                           const int* __restrict__ perm,
                                                           const unsigned int* __restrict__ edges,
                                                           const half_t* __restrict__ xw,
                                                           const float* __restrict__ dinv,
                                                           const float* __restrict__ b,
                                                           half_t* __restrict__ hp,
                                                           float* __restrict__ hf,
                                                           float* __restrict__ stats,
                                                           int n_nodes) {
    int g = (blockIdx.x & 7) >> 1;                           // feature group 0..3
    int grank = ((blockIdx.x >> 3) << 1) | (blockIdx.x & 1); // rank within group
    int lane16 = threadIdx.x & 15;
    int quadLocal = threadIdx.x >> 4;                        // 0..15
    int quadId = grank * 16 + quadLocal;
    int nquads = (gridDim.x >> 2) * 16;

    const half_t* xg = xw + (size_t)g * GSTRIDE;
    const char* xgb = (const char*)xg + lane16 * 2;
    half_t* hpg = hp + (size_t)g * GSTRIDE;
    int f = g * 16 + lane16;
    float bf = b[f];
    int base = ((threadIdx.x & 63) >> 4) * 16;               // quad's shfl window

    float s = 0.f, s2 = 0.f;
    for (int i = quadId; i < n_nodes; i += nquads) {
        int node = perm[i];
        int beg = ptrS[i];
        int c = ptrS[i + 1] - beg;
        float a0 = 0.f, a1 = 0.f, a2 = 0.f, a3 = 0.f;
        for (int j0 = 0; j0 < c; j0 += 16) {
            int m = c - j0;
            if (m > 16) m = 16;
            int ev = 0;
            if (lane16 < m) ev = (int)edges[beg + j0 + lane16];
            int j = 0;
            for (; j + 4 <= m; j += 4) {
                unsigned int u0 = (unsigned int)__shfl(ev, base + j);
                unsigned int u1 = (unsigned int)__shfl(ev, base + j + 1);
                unsigned int u2 = (unsigned int)__shfl(ev, base + j + 2);
                unsigned int u3 = (unsigned int)__shfl(ev, base + j + 3);
                float w0 = __uint_as_float((u0 & 0x7fffu) << 16);
                float w1 = __uint_as_float((u1 & 0x7fffu) << 16);
                float w2 = __uint_as_float((u2 & 0x7fffu) << 16);
                float w3 = __uint_as_float((u3 & 0x7fffu) << 16);
                float x0 = (float)*(const half_t*)(xgb + ((size_t)(u0 >> 15) << 5));
                float x1 = (float)*(const half_t*)(xgb + ((size_t)(u1 >> 15) << 5));
                float x2 = (float)*(const half_t*)(xgb + ((size_t)(u2 >> 15) << 5));
                float x3 = (float)*(const half_t*)(xgb + ((size_t)(u3 >> 15) << 5));
                a0 += w0 * x0; a1 += w1 * x1; a2 += w2 * x2; a3 += w3 * x3;
            }
            if (j < m) {
                unsigned int u = (unsigned int)__shfl(ev, base + j);
                a1 += __uint_as_float((u & 0x7fffu) << 16) *
                      (float)*(const half_t*)(xgb + ((size_t)(u >> 15) << 5));
            }
            if (j + 1 < m) {
                unsigned int u = (unsigned int)__shfl(ev, base + j + 1);
                a2 += __uint_as_float((u & 0x7fffu) << 16) *
                      (float)*(const half_t*)(xgb + ((size_t)(u >> 15) << 5));
            }
            if (j + 2 < m) {
                unsigned int u = (unsigned int)__shfl(ev, base + j + 2);
                a3 += __uint_as_float((u & 0x7fffu) << 16) *
                      (float)*(const half_t*)(xgb + ((size_t)(u >> 15) << 5));
            }
        }
        float di = dinv[node];
        float v = ((a0 + a1) + (a2 + a3))
                  + di * di * (float)xg[(size_t)node * 16 + lane16] + bf;
        if (LAST)
            hf[(size_t)node * HID + f] = v;
        else
            hpg[(size_t)node * 16 + lane16] = (half_t)v;
        s += v;
        s2 += v * v;
    }
    __shared__ float ls[256], ls2[256];
    ls[threadIdx.x] = s;
    ls2[threadIdx.x] = s2;
    __syncthreads();
    if (threadIdx.x < 16) {
        float a = 0.f, aa = 0.f;
#pragma unroll
        for (int k = 0; k < 16; k++) {
            a += ls[k * 16 + threadIdx.x];
            aa += ls2[k * 16 + threadIdx.x];
        }
        atomicAdd(&stats[g * 16 + threadIdx.x], a);
        atomicAdd(&stats[64 + g * 16 + threadIdx.x], aa);
    }
}

// ---------------- layer 3: BN + ReLU + write node_embs + segment-sum --------
__global__ __launch_bounds__(256) void bn_relu_seg_kernel(float* __restrict__ h,
                                                          const float* __restrict__ stats,
                                                          const float* __restrict__ gamma,
                                                          const float* __restrict__ beta,
                                                          const int* __restrict__ batch,
                                                          float* __restrict__ gemb,
                                                          int n_nodes) {
    int g = blockIdx.x * blockDim.x + threadIdx.x;
    int f = g & 63;
    int wave = g >> 6;
    int nwaves = (gridDim.x * blockDim.x) >> 6;
    int chunk = (n_nodes + nwaves - 1) / nwaves;
    int n0 = wave * chunk;
    int n1 = n0 + chunk;
    if (n1 > n_nodes) n1 = n_nodes;
    if (n0 >= n_nodes) return;
    float mean = stats[f] * (1.0f / N_NODES);
    float var = stats[64 + f] * (1.0f / N_NODES) - mean * mean;
    float sc = gamma[f] * rsqrtf(var + EPS);
    float sh = beta[f] - mean * sc;
    int curg = batch[n0];
    float racc = 0.f;
    for (int n = n0; n < n1; n++) {
        int bg = batch[n];
        if (bg != curg) {
            atomicAdd(&gemb[(size_t)curg * HID + f], racc);
            racc = 0.f;
            curg = bg;
        }
        size_t idx = (size_t)n * HID + f;
        float v = h[idx] * sc + sh;
        v = fmaxf(v, 0.f);
        h[idx] = v;
        racc += v;
    }
    atomicAdd(&gemb[(size_t)curg * HID + f], racc);
}

__global__ __launch_bounds__(256) void final_kernel(const float* __restrict__ gemb,
                                                    const float* __restrict__ fcW,
                                                    const float* __restrict__ fcb,
                                                    float* __restrict__ out) {
    int g = blockIdx.x * blockDim.x + threadIdx.x;
    if (g >= N_GRAPHS * N_CLS) return;
    int gr = g >> 1, c = g & 1;
    float acc = fcb[c];
#pragma unroll
    for (int k = 0; k < HID; k++) acc += gemb[gr * HID + k] * fcW[k * N_CLS + c];
    out[g] = acc;
}

// ---------------- launch ----------------

extern "C" void kernel_launch(void* const* d_in, const int* in_sizes, int n_in,
                              void* d_out, int out_size, void* d_ws, size_t ws_size,
                              hipStream_t stream) {
    const float* x    = (const float*)d_in[0];
    const int*   ei   = (const int*)d_in[1];
    const int*   batch= (const int*)d_in[2];
    const float* ew   = (const float*)d_in[3];
    const float* W1   = (const float*)d_in[4];
    const float* b1   = (const float*)d_in[5];
    const float* W2   = (const float*)d_in[6];
    const float* b2   = (const float*)d_in[7];
    const float* W3   = (const float*)d_in[8];
    const float* b3   = (const float*)d_in[9];
    const float* g1   = (const float*)d_in[10];
    const float* bt1  = (const float*)d_in[11];
    const float* g2   = (const float*)d_in[12];
    const float* bt2  = (const float*)d_in[13];
    const float* g3   = (const float*)d_in[14];
    const float* bt3  = (const float*)d_in[15];
    const float* fcW  = (const float*)d_in[16];
    const float* fcb  = (const float*)d_in[17];

    const int* row = ei;
    const int* col = ei + N_EDGES;

    // d_out layout: out [2048*2] | node_embs [100000*64] | graph_emb [2048*64]
    float* out_head  = (float*)d_out;
    float* node_embs = out_head + N_GRAPHS * N_CLS;
    float* gemb      = node_embs + (size_t)N_NODES * HID;

    // ws layout with lifetime overlays:
    //  R0 (12.8 MB): EB (CSR build) -> xwh planes (written after EB dead)
    //  R1 (12.8 MB): EA (phase A)   -> h fp16 planes (written after EA dead)
    //  R2 (6.4 MB):  final packed u32 edges
    //  R3: misc small arrays
    char* bse = (char*)d_ws;
    half_t* xwh = (half_t*)bse;                        // R0
    int2*   EB  = (int2*)bse;
    char* r1 = bse + (size_t)N_NODES * HID * 2;        // 12.8e6 (8-aligned)
    int2*   EA  = (int2*)r1;                           // R1
    half_t* hpl = (half_t*)r1;                         // h fp16 planes
    char* r2 = r1 + (size_t)N_NODES * HID * 2;
    unsigned int* edges = (unsigned int*)r2;           // 6.4e6
    char* r3 = r2 + (size_t)N_EDGES * 4;
    float* dinv  = (float*)r3;                         // 400 KB
    float* stats = dinv + N_NODES;                     // 512 B
    int*   ptr   = (int*)(stats + 128);                // (N+1) ints
    int*   histG = ptr + N_NODES + 1;                  // NBUCK*ABLOCKS
    int*   bsumA = histG + NBUCK * ABLOCKS;            // NBUCK
    int*   histD = bsumA + NBUCK + 4;                  // 256*NBLK2
    int*   rowTot = histD + 256 * NBLK2;               // 256
    int*   nodeExcl = rowTot + 256;                    // 256
    int*   edgeExcl = nodeExcl + 256;                  // 256
    int*   perm   = edgeExcl + 256;                    // N
    int*   newbase= perm + N_NODES;                    // N
    int*   ptrS   = newbase + N_NODES;                 // N+1

    const int B   = 256;
    const int gGS = 1024;   // grid-stride
    const int gGA = 2048;   // gather (mult of 8)

    // ---- CSR build: LDS counting sort, zero global atomics ----
    histA_kernel<<<ABLOCKS, B, 0, stream>>>(col, histG);
    scanS1_kernel<<<NBUCK, B, 0, stream>>>(histG, bsumA);
    topscan_kernel<<<1, 512, 0, stream>>>(bsumA, NBUCK);
    scanS3_kernel<<<NBUCK, B, 0, stream>>>(histG, bsumA, ptr);
    scatterA_kernel<<<ABLOCKS, B, 0, stream>>>(row, col, ew, histG, EA);
    bucket_kernel<<<NBUCK, B, 0, stream>>>(EA, bsumA, EB, ptr, dinv);

    // ---- degree sort of nodes ----
    histD_kernel<<<NBLK2, B, 0, stream>>>(ptr, histD);
    scanD1_kernel<<<256, 128, 0, stream>>>(histD, rowTot);
    topscanD_kernel<<<1, 256, 0, stream>>>(rowTot, nodeExcl, edgeExcl, ptrS);
    scanD3_kernel<<<256, 128, 0, stream>>>(histD, nodeExcl);
    scatterD_kernel<<<NBLK2, B, 0, stream>>>(ptr, histD, nodeExcl, edgeExcl,
                                             perm, ptrS, newbase);
    finalize_kernel<<<gGS, B, 0, stream>>>(EB, dinv, ptr, newbase, edges, N_EDGES);

    float* h3 = node_embs;  // raw (pre-BN) layer-3 activation; ends as output

    // ---- layer 1 (xwh overwrites EB region — EB dead after finalize) ----
    gemm_kernel<IN_F><<<gGS, B, 0, stream>>>(x, W1, xwh, N_NODES);
    hipMemsetAsync(stats, 0, 128 * sizeof(float), stream);
    gather_stats_kernel<false><<<gGA, B, 0, stream>>>(ptrS, perm, edges, xwh, dinv,
                                                      b1, hpl, h3, stats, N_NODES);

    // ---- layer 2 (BN1+ReLU fused into MFMA GEMM; fp16 h planes in) ----
    gemm_bn_mfma_kernel<<<gGS, B, 0, stream>>>(hpl, W2, stats, g1, bt1, xwh, N_NODES);
    hipMemsetAsync(stats, 0, 128 * sizeof(float), stream);
    gather_stats_kernel<false><<<gGA, B, 0, stream>>>(ptrS, perm, edges, xwh, dinv,
                                                      b2, hpl, h3, stats, N_NODES);

    // ---- layer 3 (BN2+ReLU fused into MFMA GEMM) ----
    gemm_bn_mfma_kernel<<<gGS, B, 0, stream>>>(hpl, W3, stats, g2, bt2, xwh, N_NODES);
    hipMemsetAsync(stats, 0, 128 * sizeof(float), stream);
    gather_stats_kernel<true><<<gGA, B, 0, stream>>>(ptrS, perm, edges, xwh, dinv,
                                                     b3, hpl, h3, stats, N_NODES);

    // ---- BN3 + ReLU + node_embs + segment-sum ----
    hipMemsetAsync(gemb, 0, (size_t)N_GRAPHS * HID * sizeof(float), stream);
    bn_relu_seg_kernel<<<gGS, B, 0, stream>>>(h3, stats, g3, bt3, batch, gemb, N_NODES);

    // ---- readout ----
    final_kernel<<<(N_GRAPHS * N_CLS + B - 1) / B, B, 0, stream>>>(gemb, fcW, fcb, out_head);
}